// Round 1
// baseline (1088.192 us; speedup 1.0000x reference)
//
#include <hip/hip_runtime.h>

// GAT attention aggregator — algebraically refactored, streaming form.
// Key identity: softmax coefs depend on logits = X@(W@a), and the output is
//   relu(h_self + sum_r coef_r (X@W)_r + b) = relu((self + sum_r coef_r X_r)@W + b).
// So the heavy per-node H=X@W GEMM is eliminated:
//   prep : wa = W@a (128 floats), Wt = W^T bf16 (for the epilogue GEMM)
//   pass1: per node, stream 32 neigh rows once (bf16 LDS), logits = X@wa via 8
//          broadcast-B MFMAs, fp32 softmax, z = coef^T X (VALU, SGPR coefs),
//          write y = self + z into `out`  (memory-bound: ~870 MB total)
//   pass2: out = relu(Y@W + b), dense 50000x128x128 bf16 MFMA GEMM, in-place
//          per 16-row panel (each wave reads only the rows it writes).
// pass1: 1-wave blocks, 12/CU (LDS 8.9 KB, VGPR<=168), T14 prefetch: next
// node's 17 loads issued before current node's math -> loads always in flight.

constexpr int D   = 128;
constexpr int KN  = 32;
constexpr int LDX = 136;   // padded X row (bf16 elems): 272 B = 16B-aligned, 2-way banks max

typedef __bf16 bf16;
typedef __attribute__((ext_vector_type(8))) __bf16 bf16x8;
typedef __attribute__((ext_vector_type(4))) float  f32x4;

// ---- one-shot prep: Wt[n][k] = W[k][n] (bf16), wa[k] = sum_n W[k][n] a[n] ----
__global__ void prep_kernel(const float* __restrict__ W,
                            const float* __restrict__ attn,
                            bf16* __restrict__ Wt,
                            float* __restrict__ wa)
{
  const int i = blockIdx.x * 256 + threadIdx.x;
  if (i < D * D) {
    const int n = i >> 7, k = i & 127;
    Wt[i] = (bf16)W[(k << 7) + n];
  }
  if (i < D) {
    float s = 0.f;
    for (int n = 0; n < D; ++n) s += W[i * D + n] * attn[n];
    wa[i] = s;
  }
}

// ---- pass 1: streaming attention in input space ----
__global__ __launch_bounds__(64, 3)
void gat_pass1(const float* __restrict__ selfv,
               const float* __restrict__ neighv,
               const float* __restrict__ Wfp,
               const float* __restrict__ attnv,
               const float* __restrict__ wa_g,
               float* __restrict__ ybuf,
               int nnodes, int npn, int use_ws)
{
  __shared__ __align__(16) bf16 Xs[KN * LDX];  // 8704 B, this wave's node tile
  __shared__ __align__(16) bf16 wab[D];        // wa as bf16 (MFMA B operand)

  const int lane = threadIdx.x;                // block = 1 wave
  const int q = lane >> 4, l15 = lane & 15;

  // per-lane wa at cols 2*lane, 2*lane+1 (fp32) + bf16 copy in LDS
  float wa0, wa1;
  if (use_ws) {
    float2 w2 = *(const float2*)&wa_g[2 * lane];
    wa0 = w2.x; wa1 = w2.y;
  } else {
    float s0 = 0.f, s1 = 0.f;
    for (int n = 0; n < D; ++n) {            // fallback: L2-resident W, once/block
      const float an = attnv[n];
      s0 += Wfp[(2 * lane) * D + n] * an;
      s1 += Wfp[(2 * lane + 1) * D + n] * an;
    }
    wa0 = s0; wa1 = s1;
  }
  wab[2 * lane]     = (bf16)wa0;
  wab[2 * lane + 1] = (bf16)wa1;

  const float4* neigh4 = (const float4*)neighv;
  const float2* self2  = (const float2*)selfv;
  const int base = blockIdx.x * npn;
  if (base >= nnodes) return;

  float4 st[16];     // prefetch regs: this lane's 256 B slice of next node
  float2 selfr;
  {
    const float4* p = neigh4 + (size_t)base * (KN * D / 4);
    #pragma unroll
    for (int c = 0; c < 8; ++c) {
      st[2 * c]     = p[2 * (lane + 64 * c)];
      st[2 * c + 1] = p[2 * (lane + 64 * c) + 1];
    }
    selfr = self2[(size_t)base * (D / 2) + lane];
  }

  for (int i = 0; i < npn; ++i) {
    const int node = base + i;
    if (node >= nnodes) break;               // wave-uniform

    // ---- cvt + LDS write (consumes st; 8x ds_write_b128) ----
    #pragma unroll
    for (int c = 0; c < 8; ++c) {
      const int cc = lane + 64 * c;
      const int row = cc >> 4, c8 = cc & 15;
      const float4 va = st[2 * c], vb = st[2 * c + 1];
      bf16x8 b = { (bf16)va.x, (bf16)va.y, (bf16)va.z, (bf16)va.w,
                   (bf16)vb.x, (bf16)vb.y, (bf16)vb.z, (bf16)vb.w };
      *(bf16x8*)&Xs[row * LDX + c8 * 8] = b;
    }
    const float2 sv = selfr;

    // ---- T14: issue next node's global loads now; latency hides under math ----
    if (i + 1 < npn && node + 1 < nnodes) {
      const float4* p = neigh4 + (size_t)(node + 1) * (KN * D / 4);
      #pragma unroll
      for (int c = 0; c < 8; ++c) {
        st[2 * c]     = p[2 * (lane + 64 * c)];
        st[2 * c + 1] = p[2 * (lane + 64 * c) + 1];
      }
      selfr = self2[(size_t)(node + 1) * (D / 2) + lane];
    }

    // ---- logits = X @ wa via MFMA with B broadcast across cols:
    //      D[r][c] = sum_k X[r][k] * wab[k]  => logit_r replicated over l15.
    //      acc0: rows q*4+r, acc1: rows 16+q*4+r (C/D layout col=l15, row=q*4+r)
    f32x4 acc0 = {0.f, 0.f, 0.f, 0.f}, acc1 = {0.f, 0.f, 0.f, 0.f};
    #pragma unroll
    for (int ks = 0; ks < 4; ++ks) {
      const bf16x8 B  = *(const bf16x8*)&wab[ks * 32 + q * 8];
      const bf16x8 A0 = *(const bf16x8*)&Xs[l15 * LDX + ks * 32 + q * 8];
      const bf16x8 A1 = *(const bf16x8*)&Xs[(16 + l15) * LDX + ks * 32 + q * 8];
      acc0 = __builtin_amdgcn_mfma_f32_16x16x32_bf16(A0, B, acc0, 0, 0, 0);
      acc1 = __builtin_amdgcn_mfma_f32_16x16x32_bf16(A1, B, acc1, 0, 0, 0);
    }

    // ---- self logit: selfv . wa (fp32, full-wave butterfly) ----
    float sl = sv.x * wa0 + sv.y * wa1;
    sl += __shfl_xor(sl, 1);  sl += __shfl_xor(sl, 2);  sl += __shfl_xor(sl, 4);
    sl += __shfl_xor(sl, 8);  sl += __shfl_xor(sl, 16); sl += __shfl_xor(sl, 32);

    // ---- leaky_relu + fp32 softmax over 32 neighbor rows ----
    float e0[4], e1[4], mx = -3.4e38f;
    #pragma unroll
    for (int r = 0; r < 4; ++r) {
      float t0 = acc0[r] + sl; t0 = t0 > 0.f ? t0 : 0.2f * t0;
      float t1 = acc1[r] + sl; t1 = t1 > 0.f ? t1 : 0.2f * t1;
      e0[r] = t0; e1[r] = t1;
      mx = fmaxf(mx, fmaxf(t0, t1));
    }
    mx = fmaxf(mx, __shfl_xor(mx, 16));
    mx = fmaxf(mx, __shfl_xor(mx, 32));
    float s = 0.f;
    #pragma unroll
    for (int r = 0; r < 4; ++r) {
      e0[r] = __expf(e0[r] - mx); e1[r] = __expf(e1[r] - mx);
      s += e0[r] + e1[r];
    }
    s += __shfl_xor(s, 16); s += __shfl_xor(s, 32);
    const float inv = 1.0f / s;
    #pragma unroll
    for (int r = 0; r < 4; ++r) { e0[r] *= inv; e1[r] *= inv; }

    // ---- coefs -> SGPRs via readlane (row k lives in lane group (k>>2)&3) ----
    float cf[32];
    #pragma unroll
    for (int k = 0; k < 32; ++k) {
      const int src = ((k >> 2) & 3) * 16;
      const float v = (k < 16) ? e0[k & 3] : e1[k & 3];
      cf[k] = __int_as_float(__builtin_amdgcn_readlane(__float_as_int(v), src));
    }

    // ---- z = coef^T X (lane owns cols 2*lane, 2*lane+1), y = self + z ----
    float z0 = 0.f, z1 = 0.f;
    #pragma unroll
    for (int r = 0; r < 32; ++r) {
      const unsigned u = *(const unsigned*)&Xs[r * LDX + 2 * lane];
      z0 += cf[r] * __uint_as_float(u << 16);
      z1 += cf[r] * __uint_as_float(u & 0xffff0000u);
    }
    const float2 y = { sv.x + z0, sv.y + z1 };
    *(float2*)&ybuf[(size_t)node * D + 2 * lane] = y;
  }
}

// ---- pass 2: out = relu(Y @ W + bias), in-place per 16-row panel.
//      A operand double-bf16 compensated (hi+lo) so Y rounding ~ fp32. ----
__global__ __launch_bounds__(256, 2)
void gat_pass2(const bf16* __restrict__ Wt_g,
               const float* __restrict__ Wfp,
               const float* __restrict__ biasp,
               float* __restrict__ out,
               int nnodes, int use_ws)
{
  const int tid = threadIdx.x, w = tid >> 6, lane = tid & 63;
  const int q = lane >> 4, l15 = lane & 15;
  const int t = blockIdx.x * 4 + w;
  const int row0 = t * 16;
  if (row0 >= nnodes) return;

  float bv[8];
  #pragma unroll
  for (int nt = 0; nt < 8; ++nt) bv[nt] = biasp[nt * 16 + l15];

  const int arow = row0 + l15;
  const bool rv = arow < nnodes;

  f32x4 acc[8];
  #pragma unroll
  for (int nt = 0; nt < 8; ++nt) acc[nt] = (f32x4){0.f, 0.f, 0.f, 0.f};

  #pragma unroll
  for (int ks = 0; ks < 4; ++ks) {
    float a[8];
    if (rv) {
      const float4 v0 = *(const float4*)&out[(size_t)arow * D + ks * 32 + q * 8];
      const float4 v1 = *(const float4*)&out[(size_t)arow * D + ks * 32 + q * 8 + 4];
      a[0] = v0.x; a[1] = v0.y; a[2] = v0.z; a[3] = v0.w;
      a[4] = v1.x; a[5] = v1.y; a[6] = v1.z; a[7] = v1.w;
    } else {
      #pragma unroll
      for (int j = 0; j < 8; ++j) a[j] = 0.f;
    }
    bf16x8 Ah, Al;
    #pragma unroll
    for (int j = 0; j < 8; ++j) {
      const bf16 h = (bf16)a[j];
      Ah[j] = h;
      Al[j] = (bf16)(a[j] - (float)h);
    }
    #pragma unroll
    for (int nt = 0; nt < 8; ++nt) {
      bf16x8 B;
      if (use_ws) {
        B = *(const bf16x8*)&Wt_g[(nt * 16 + l15) * D + ks * 32 + q * 8];
      } else {
        #pragma unroll
        for (int j = 0; j < 8; ++j)
          B[j] = (bf16)Wfp[(size_t)(ks * 32 + q * 8 + j) * D + nt * 16 + l15];
      }
      acc[nt] = __builtin_amdgcn_mfma_f32_16x16x32_bf16(Ah, B, acc[nt], 0, 0, 0);
      acc[nt] = __builtin_amdgcn_mfma_f32_16x16x32_bf16(Al, B, acc[nt], 0, 0, 0);
    }
  }

  #pragma unroll
  for (int nt = 0; nt < 8; ++nt) {
    #pragma unroll
    for (int r = 0; r < 4; ++r) {
      const int row = row0 + q * 4 + r;
      if (row < nnodes)
        out[(size_t)row * D + nt * 16 + l15] = fmaxf(acc[nt][r] + bv[nt], 0.f);
    }
  }
}

extern "C" void kernel_launch(void* const* d_in, const int* in_sizes, int n_in,
                              void* d_out, int out_size, void* d_ws, size_t ws_size,
                              hipStream_t stream) {
  const float* selfv  = (const float*)d_in[0];
  const float* neighv = (const float*)d_in[1];
  const float* W      = (const float*)d_in[2];
  const float* attn   = (const float*)d_in[3];
  const float* biasp  = (const float*)d_in[4];
  float* out = (float*)d_out;
  const int nnodes = in_sizes[0] / D;

  const size_t need = (size_t)D * D * sizeof(bf16) + D * sizeof(float);
  const int use_ws = (ws_size >= need) ? 1 : 0;
  bf16*  Wt_g = (bf16*)d_ws;
  float* wa_g = (float*)((char*)d_ws + (size_t)D * D * sizeof(bf16));
  if (use_ws)
    prep_kernel<<<(D * D + 255) / 256, 256, 0, stream>>>(W, attn, Wt_g, wa_g);

  const int nblk = 3072;                               // 1-wave blocks, 12/CU
  const int npn  = (nnodes + nblk - 1) / nblk;
  gat_pass1<<<nblk, 64, 0, stream>>>(selfv, neighv, W, attn, wa_g, out,
                                     nnodes, npn, use_ws);

  const int ntiles = (nnodes + 15) / 16;               // 16-row panels
  gat_pass2<<<(ntiles + 3) / 4, 256, 0, stream>>>(Wt_g, W, biasp, out,
                                                  nnodes, use_ws);
}